// Round 2
// baseline (361.342 us; speedup 1.0000x reference)
//
#include <hip/hip_runtime.h>
#include <math.h>

// ReaReaConv via linearity factorization + direct-CSR binning:
//   u[b,t,:] = dis_t^2 * x[b,t,:] + sum_e norm_e*(1-f_be)*x[b,src_e,:]
//   v[b,t,:] =                      sum_e norm_e*   f_be *x[b,src_e,:]
//   out      = bias + u @ Wc^T + v @ Wd^T   (MFMA bf16, M=BN,K=128,N=64)
// CSR build: global-atomic degree histogram -> per-block scan (row starts)
// -> global-atomic scatter of 4B {src | q<<17} entries. nodeinfo format is
// unchanged: {rsqrt(deg+1), flux0, flux1, deg<<21|rowstart}, rowstart<2^21.

constexpr int C = 64;

typedef short short8 __attribute__((ext_vector_type(8)));
typedef float f32x4 __attribute__((ext_vector_type(4)));

__device__ __forceinline__ unsigned pack_bf16x2(float a, float b) {
    unsigned ua = __float_as_uint(a);
    ua = (ua + 0x7fffu + ((ua >> 16) & 1u)) >> 16;  // RNE
    unsigned ub = __float_as_uint(b);
    ub = (ub + 0x7fffu + ((ub >> 16) & 1u)) >> 16;
    return ua | (ub << 16);
}
__device__ __forceinline__ float bflo(unsigned p) { return __uint_as_float(p << 16); }
__device__ __forceinline__ float bfhi(unsigned p) { return __uint_as_float(p & 0xffff0000u); }

// ---- K1: x -> packed bf16x2 (natural pairs) + zero degree counters (+cursor)
__global__ __launch_bounds__(256) void convert_kernel(
    const float* __restrict__ x, unsigned* __restrict__ xb2, int nwords,
    int* __restrict__ degc, int N) {
    int i = blockIdx.x * blockDim.x + threadIdx.x;
    if (i <= N) degc[i] = 0;  // degc has N+1 ints; [N] is the global cursor
    int stride = gridDim.x * blockDim.x;
    const float2* x2 = (const float2*)x;
    for (int w = i; w < nwords; w += stride) {
        float2 xv = x2[w];
        xb2[w] = pack_bf16x2(xv.x, xv.y);
    }
}

// ---- K2: per-target degree histogram (global atomics, 200KB L2-resident)
__global__ __launch_bounds__(256) void degcount_kernel(
    const int* __restrict__ tgt, int* __restrict__ degc, int E) {
    int i = blockIdx.x * blockDim.x + threadIdx.x;
    int stride = gridDim.x * blockDim.x;
    for (int e = i; e < E; e += stride) atomicAdd(&degc[tgt[e]], 1);
}

// ---- K3: per-block scan of degrees -> row starts; emit nodeinfo; leave
// degc[n] = rowstart as the scatter cursor.
__global__ __launch_bounds__(256) void scan_kernel(
    int* __restrict__ degc, const float* __restrict__ flux,
    float4* __restrict__ nodeinfo, int N) {
    __shared__ int sc[256];
    __shared__ int sbase;
    const int tid = threadIdx.x;
    const int n = blockIdx.x * 256 + tid;
    int dg = (n < N) ? degc[n] : 0;
    sc[tid] = dg;
    __syncthreads();
    for (int off = 1; off < 256; off <<= 1) {  // Hillis-Steele inclusive
        int v = (tid >= off) ? sc[tid - off] : 0;
        __syncthreads();
        sc[tid] += v;
        __syncthreads();
    }
    if (tid == 255) sbase = atomicAdd(&degc[N], sc[255]);
    __syncthreads();
    if (n < N) {
        int rs = sbase + sc[tid] - dg;  // exclusive + block base
        degc[n] = rs;                   // scatter cursor
        float4 ni;
        ni.x = rsqrtf((float)(dg + 1));
        ni.y = flux[n];
        ni.z = flux[N + n];
        ni.w = __int_as_float((dg << 21) | rs);  // rs < 1.6M < 2^21
        nodeinfo[n] = ni;
    }
}

// ---- K4: scatter edges to final CSR slots (4B entries, L2-resident array)
__global__ __launch_bounds__(256) void scatter_kernel(
    const int* __restrict__ src, const int* __restrict__ tgt,
    const float* __restrict__ fdo, int* __restrict__ cursors,
    unsigned* __restrict__ epack, int E) {
    int i = blockIdx.x * blockDim.x + threadIdx.x;
    int stride = gridDim.x * blockDim.x;
    for (int e = i; e < E; e += stride) {
        int t = tgt[e];
        int pos = atomicAdd(&cursors[t], 1);
        unsigned q = (unsigned)(fdo[e] * 32767.0f + 0.5f);  // 15-bit
        epack[pos] = (unsigned)src[e] | (q << 17);
    }
}

// ---- K5: per-target aggregation, wave per node, 4 edges per iteration.
// Lane = (e2 = lane>>4: edge sub-index, g = batch, p = 16B chunk of the row).
// Phase 1: lane e decodes edge e, ONE float4 nodeinfo gather, writes both
// batches' coefs {src<<7, cc, cd} to wave-private LDS (zero-pad to 4).
// Phase 2: per iter each lane does broadcast b128 coef read + one dwordx4
// x gather (8 channels) + 16 FMA. Final shfl_xor(16/32) merges e2 partials.
__global__ __launch_bounds__(256) void aggregate_kernel(
    const float4* __restrict__ nodeinfo, const unsigned* __restrict__ epackFine,
    const unsigned* __restrict__ xb2, unsigned* __restrict__ up,
    unsigned* __restrict__ vp, int N) {
    const int lane = threadIdx.x & 63;
    const int wslot = threadIdx.x >> 6;
    const int node = blockIdx.x * 4 + wslot;
    __shared__ float4 s_e[4][2][64];
    if (node >= N) return;
    const int e2 = lane >> 4;       // 0..3
    const int q16 = lane & 15;
    const int g = q16 >> 3;         // batch
    const int p = q16 & 7;          // words 4p..4p+3 = channels 8p..8p+7
    float4 ni = nodeinfo[node];
    const unsigned wbits = (unsigned)__float_as_int(ni.w);
    const int start = (int)(wbits & 0x1FFFFFu);
    const int end = start + (int)(wbits >> 21);
    const float dt = ni.x, f0t = ni.y, f1t = ni.z;
    const char* xbg = (const char*)xb2 + (size_t)g * N * 128 + p * 16;
    float au[8] = {0, 0, 0, 0, 0, 0, 0, 0};
    float av[8] = {0, 0, 0, 0, 0, 0, 0, 0};
    for (int base = start; base < end; base += 64) {
        int cnt = min(64, end - base);
        int cntp = (cnt + 3) & ~3;
        if (lane < cnt) {
            unsigned pe = epackFine[base + lane];
            int s = (int)(pe & 0x1FFFFu);
            float fd = (float)(pe >> 17) * (1.0f / 32767.0f);
            float4 nis = nodeinfo[s];
            float nrm = nis.x * dt;
            float p0 = nis.y * f0t;
            float p1 = nis.z * f1t;
            float k0 = 1.0f / (1.0f + __expf(-2.0f * p0));  // (1+tanh)/2
            float k1 = 1.0f / (1.0f + __expf(-2.0f * p1));
            float w = 2.0f * fd - 1.0f;
            float f0 = fmaf(k0, w, 1.0f - fd);
            float f1 = fmaf(k1, w, 1.0f - fd);
            float soff = __int_as_float(s << 7);
            s_e[wslot][0][lane] = make_float4(soff, nrm * (1.0f - f0), nrm * f0, 0.f);
            s_e[wslot][1][lane] = make_float4(soff, nrm * (1.0f - f1), nrm * f1, 0.f);
        } else if (lane < cntp) {
            float4 z = make_float4(0.f, 0.f, 0.f, 0.f);
            s_e[wslot][0][lane] = z;
            s_e[wslot][1][lane] = z;
        }
        // wave-private LDS: in-wave write->read ordering via lgkmcnt only
        float4 r0 = s_e[wslot][g][e2];
        uint4 xwN = *(const uint4*)(xbg + __float_as_int(r0.x));
        float ccN = r0.y, cdN = r0.z;
        for (int j = 4; j < cntp; j += 4) {
            uint4 xw = xwN;
            float cc = ccN, cd = cdN;
            float4 r2 = s_e[wslot][g][j + e2];
            xwN = *(const uint4*)(xbg + __float_as_int(r2.x));  // prefetch
            ccN = r2.y; cdN = r2.z;
#pragma unroll
            for (int w = 0; w < 4; ++w) {
                unsigned xp = (&xw.x)[w];
                float lo = bflo(xp), hi = bfhi(xp);
                au[2 * w] = fmaf(cc, lo, au[2 * w]);
                au[2 * w + 1] = fmaf(cc, hi, au[2 * w + 1]);
                av[2 * w] = fmaf(cd, lo, av[2 * w]);
                av[2 * w + 1] = fmaf(cd, hi, av[2 * w + 1]);
            }
        }
#pragma unroll
        for (int w = 0; w < 4; ++w) {
            unsigned xp = (&xwN.x)[w];
            float lo = bflo(xp), hi = bfhi(xp);
            au[2 * w] = fmaf(ccN, lo, au[2 * w]);
            au[2 * w + 1] = fmaf(ccN, hi, au[2 * w + 1]);
            av[2 * w] = fmaf(cdN, lo, av[2 * w]);
            av[2 * w + 1] = fmaf(cdN, hi, av[2 * w + 1]);
        }
    }
    // merge the 4 edge-subset partials (lanes differing in bits 4,5)
#pragma unroll
    for (int k = 0; k < 8; ++k) {
        au[k] += __shfl_xor(au[k], 16, 64);
        au[k] += __shfl_xor(au[k], 32, 64);
        av[k] += __shfl_xor(av[k], 16, 64);
        av[k] += __shfl_xor(av[k], 32, 64);
    }
    if (e2 == 0) {
        uint4 xs = *(const uint4*)(xbg + ((size_t)node << 7));  // self-loop
        float d2 = dt * dt;
#pragma unroll
        for (int w = 0; w < 4; ++w) {
            unsigned xp = (&xs.x)[w];
            au[2 * w] = fmaf(d2, bflo(xp), au[2 * w]);
            au[2 * w + 1] = fmaf(d2, bfhi(xp), au[2 * w + 1]);
        }
        uint4 uo, vo;
        uo.x = pack_bf16x2(au[0], au[1]);
        uo.y = pack_bf16x2(au[2], au[3]);
        uo.z = pack_bf16x2(au[4], au[5]);
        uo.w = pack_bf16x2(au[6], au[7]);
        vo.x = pack_bf16x2(av[0], av[1]);
        vo.y = pack_bf16x2(av[2], av[3]);
        vo.z = pack_bf16x2(av[4], av[5]);
        vo.w = pack_bf16x2(av[6], av[7]);
        size_t wo = ((size_t)(g * N + node)) * 32 + 4 * p;
        *(uint4*)(up + wo) = uo;
        *(uint4*)(vp + wo) = vo;
    }
}

// ---- K6: MFMA GEMM. out = [u v] @ [Wc;Wd]^T + bias.
__device__ __forceinline__ short8 make_bfrag(const float* __restrict__ row, int off) {
    const float4* p = (const float4*)(row + off);
    float4 lo = p[0], hi = p[1];
    uint4 w;
    w.x = pack_bf16x2(lo.x, lo.y);
    w.y = pack_bf16x2(lo.z, lo.w);
    w.z = pack_bf16x2(hi.x, hi.y);
    w.w = pack_bf16x2(hi.z, hi.w);
    return __builtin_bit_cast(short8, w);
}

__global__ __launch_bounds__(256) void gemm_mfma_kernel(
    const unsigned* __restrict__ up, const unsigned* __restrict__ vp,
    const float* __restrict__ Wc, const float* __restrict__ Wd,
    const float* __restrict__ bias, float* __restrict__ out, int ntiles) {
    const int lane = threadIdx.x & 63;
    const int nl = lane & 15;
    const int quad = lane >> 4;
    const int wave = blockIdx.x * 4 + (threadIdx.x >> 6);
    const int nwaves = gridDim.x * 4;

    short8 bf[4][4];
    float bt[4];
#pragma unroll
    for (int t = 0; t < 4; ++t) {
        int n = 16 * t + nl;
        const float* wcr = Wc + n * 64;
        const float* wdr = Wd + n * 64;
        bf[0][t] = make_bfrag(wcr, quad * 8);
        bf[1][t] = make_bfrag(wcr, 32 + quad * 8);
        bf[2][t] = make_bfrag(wdr, quad * 8);
        bf[3][t] = make_bfrag(wdr, 32 + quad * 8);
        bt[t] = bias[n];
    }

    for (int tile = wave; tile < ntiles; tile += nwaves) {
        int row = tile * 16 + nl;
        const uint4* ur = (const uint4*)(up + (size_t)row * 32);
        const uint4* vr = (const uint4*)(vp + (size_t)row * 32);
        short8 a0 = __builtin_bit_cast(short8, ur[quad]);
        short8 a1 = __builtin_bit_cast(short8, ur[4 + quad]);
        short8 a2 = __builtin_bit_cast(short8, vr[quad]);
        short8 a3 = __builtin_bit_cast(short8, vr[4 + quad]);
        f32x4 acc[4];
#pragma unroll
        for (int t = 0; t < 4; ++t) {
            f32x4 z = {0.f, 0.f, 0.f, 0.f};
            acc[t] = __builtin_amdgcn_mfma_f32_16x16x32_bf16(a0, bf[0][t], z, 0, 0, 0);
            acc[t] = __builtin_amdgcn_mfma_f32_16x16x32_bf16(a1, bf[1][t], acc[t], 0, 0, 0);
            acc[t] = __builtin_amdgcn_mfma_f32_16x16x32_bf16(a2, bf[2][t], acc[t], 0, 0, 0);
            acc[t] = __builtin_amdgcn_mfma_f32_16x16x32_bf16(a3, bf[3][t], acc[t], 0, 0, 0);
        }
        float* ob = out + ((size_t)(tile * 16 + quad * 4) << 6);
#pragma unroll
        for (int t = 0; t < 4; ++t) {
            int col = 16 * t + nl;
#pragma unroll
            for (int r = 0; r < 4; ++r)
                ob[(r << 6) + col] = acc[t][r] + bt[t];
        }
    }
}

extern "C" void kernel_launch(void* const* d_in, const int* in_sizes, int n_in,
                              void* d_out, int out_size, void* d_ws, size_t ws_size,
                              hipStream_t stream) {
    const float* x = (const float*)d_in[0];
    const int* ei = (const int*)d_in[1];
    const float* fdo = (const float*)d_in[2];
    const float* flux = (const float*)d_in[3];
    const float* Wc = (const float*)d_in[4];
    const float* Wd = (const float*)d_in[5];
    const float* bias = (const float*)d_in[6];
    float* out = (float*)d_out;

    const int E = in_sizes[2];
    const int BN = in_sizes[3];
    const int N = BN / 2;

    auto align = [](size_t o) { return (o + 255) & ~(size_t)255; };
    char* ws = (char*)d_ws;
    size_t o = 0;
    int* degc = (int*)(ws + o);                    o = align(o + (size_t)(N + 1) * 4);
    float4* nodeinfo = (float4*)(ws + o);          o = align(o + (size_t)N * 16);
    unsigned* epack = (unsigned*)(ws + o);         o = align(o + (size_t)E * 4);
    unsigned* xb2 = (unsigned*)(ws + o);           o = align(o + (size_t)BN * 32 * 4);
    unsigned* up = (unsigned*)(ws + o);            o = align(o + (size_t)BN * 32 * 4);
    unsigned* vp = (unsigned*)(ws + o);            o += (size_t)BN * 32 * 4;
    // total ~46 MB

    const int* srcp = ei;
    const int* tgtp = ei + E;

    convert_kernel<<<2048, 256, 0, stream>>>(x, xb2, BN * 32, degc, N);
    degcount_kernel<<<2048, 256, 0, stream>>>(tgtp, degc, E);
    scan_kernel<<<(N + 255) / 256, 256, 0, stream>>>(degc, flux, nodeinfo, N);
    scatter_kernel<<<2048, 256, 0, stream>>>(srcp, tgtp, fdo, degc, epack, E);
    aggregate_kernel<<<(N + 3) / 4, 256, 0, stream>>>(nodeinfo, epack, xb2,
                                                      up, vp, N);
    gemm_mfma_kernel<<<512, 256, 0, stream>>>(up, vp, Wc, Wd, bias, out, BN / 16);
}

// Round 3
// 322.144 us; speedup vs baseline: 1.1217x; 1.1217x over previous
//
#include <hip/hip_runtime.h>
#include <math.h>

// ReaReaConv via linearity factorization + XCD-partitioned direct-CSR binning:
//   u[b,t,:] = dis_t^2 * x[b,t,:] + sum_e norm_e*(1-f_be)*x[b,src_e,:]
//   v[b,t,:] =                      sum_e norm_e*   f_be *x[b,src_e,:]
//   out      = bias + u @ Wc^T + v @ Wd^T   (MFMA bf16, M=BN,K=128,N=64)
// CSR build: degree histogram -> per-block scan (row starts) -> scatter of
// 4B {src | q<<17} entries. degcount & scatter are partitioned by target
// range r = blockIdx&7 (round-robin block->XCD): every atomic / epack line
// has a single-XCD owner, eliminating cross-XCD line ping-pong (the 16x
// WRITE_SIZE amplification + ~240us seen with unpartitioned atomics).
// nodeinfo: {rsqrt(deg+1), flux0, flux1, deg<<21|rowstart}, rowstart<2^21.

constexpr int C = 64;

typedef short short8 __attribute__((ext_vector_type(8)));
typedef float f32x4 __attribute__((ext_vector_type(4)));

__device__ __forceinline__ unsigned pack_bf16x2(float a, float b) {
    unsigned ua = __float_as_uint(a);
    ua = (ua + 0x7fffu + ((ua >> 16) & 1u)) >> 16;  // RNE
    unsigned ub = __float_as_uint(b);
    ub = (ub + 0x7fffu + ((ub >> 16) & 1u)) >> 16;
    return ua | (ub << 16);
}
__device__ __forceinline__ float bflo(unsigned p) { return __uint_as_float(p << 16); }
__device__ __forceinline__ float bfhi(unsigned p) { return __uint_as_float(p & 0xffff0000u); }

// ---- K1: x -> packed bf16x2 (natural pairs) + zero degree counters (+cursor)
__global__ __launch_bounds__(256) void convert_kernel(
    const float* __restrict__ x, unsigned* __restrict__ xb2, int nwords,
    int* __restrict__ degc, int N) {
    int i = blockIdx.x * blockDim.x + threadIdx.x;
    if (i <= N) degc[i] = 0;  // degc has N+1 ints; [N] is the global cursor
    int stride = gridDim.x * blockDim.x;
    const float2* x2 = (const float2*)x;
    for (int w = i; w < nwords; w += stride) {
        float2 xv = x2[w];
        xb2[w] = pack_bf16x2(xv.x, xv.y);
    }
}

// ---- K2: per-target degree histogram, XCD-partitioned by target range.
// Blocks with the same (blockIdx&7) co-reside on one XCD (round-robin
// dispatch) and exclusively own node range [r*W, r*W+W): their atomics hit
// XCD-local L2 lines only. tgt is read 8x (6.4MB, L3-resident -> cheap).
__global__ __launch_bounds__(256) void degcount_kernel(
    const int* __restrict__ tgt, int* __restrict__ degc, int E, int N, int W) {
    const int r = blockIdx.x & 7;
    const int lo = r * W;
    const int hi = min(lo + W, N);
    const int gi = blockIdx.x >> 3;
    const int nthr = (gridDim.x >> 3) * 256;
    const int idx = gi * 256 + threadIdx.x;
    const int4* t4 = (const int4*)tgt;
    const int n4 = E >> 2;
    for (int i = idx; i < n4; i += nthr) {
        int4 t = t4[i];
        if (t.x >= lo && t.x < hi) atomicAdd(&degc[t.x], 1);
        if (t.y >= lo && t.y < hi) atomicAdd(&degc[t.y], 1);
        if (t.z >= lo && t.z < hi) atomicAdd(&degc[t.z], 1);
        if (t.w >= lo && t.w < hi) atomicAdd(&degc[t.w], 1);
    }
    for (int e = (n4 << 2) + idx; e < E; e += nthr) {
        int t = tgt[e];
        if (t >= lo && t < hi) atomicAdd(&degc[t], 1);
    }
}

// ---- K3: per-block scan of degrees -> row starts; emit nodeinfo; leave
// degc[n] = rowstart as the scatter cursor. Block bases via one global
// atomic (order-scrambled across blocks, but each 256-node block's epack
// region is contiguous and single-range-owned, so locality is preserved).
__global__ __launch_bounds__(256) void scan_kernel(
    int* __restrict__ degc, const float* __restrict__ flux,
    float4* __restrict__ nodeinfo, int N) {
    __shared__ int sc[256];
    __shared__ int sbase;
    const int tid = threadIdx.x;
    const int n = blockIdx.x * 256 + tid;
    int dg = (n < N) ? degc[n] : 0;
    sc[tid] = dg;
    __syncthreads();
    for (int off = 1; off < 256; off <<= 1) {  // Hillis-Steele inclusive
        int v = (tid >= off) ? sc[tid - off] : 0;
        __syncthreads();
        sc[tid] += v;
        __syncthreads();
    }
    if (tid == 255) sbase = atomicAdd(&degc[N], sc[255]);
    __syncthreads();
    if (n < N) {
        int rs = sbase + sc[tid] - dg;  // exclusive + block base
        degc[n] = rs;                   // scatter cursor
        float4 ni;
        ni.x = rsqrtf((float)(dg + 1));
        ni.y = flux[n];
        ni.z = flux[N + n];
        ni.w = __int_as_float((dg << 21) | rs);  // rs < 1.6M < 2^21
        nodeinfo[n] = ni;
    }
}

// ---- K4: scatter edges to final CSR slots, XCD-partitioned like K2.
// All writes to a node's epack lines come from its owning range's blocks
// (one XCD) -> lines stay in that L2 until final writeback (~6.4MB total).
__global__ __launch_bounds__(256) void scatter_kernel(
    const int* __restrict__ src, const int* __restrict__ tgt,
    const float* __restrict__ fdo, int* __restrict__ cursors,
    unsigned* __restrict__ epack, int E, int N, int W) {
    const int r = blockIdx.x & 7;
    const int lo = r * W;
    const int hi = min(lo + W, N);
    const int gi = blockIdx.x >> 3;
    const int nthr = (gridDim.x >> 3) * 256;
    const int idx = gi * 256 + threadIdx.x;
    const int4* t4 = (const int4*)tgt;
    const int n4 = E >> 2;
    for (int i = idx; i < n4; i += nthr) {
        int4 t = t4[i];
        int e = i << 2;
#pragma unroll
        for (int k = 0; k < 4; ++k) {
            int tk = (&t.x)[k];
            if (tk >= lo && tk < hi) {
                int pos = atomicAdd(&cursors[tk], 1);
                unsigned q = (unsigned)(fdo[e + k] * 32767.0f + 0.5f);  // 15-bit
                epack[pos] = (unsigned)src[e + k] | (q << 17);
            }
        }
    }
    for (int e = (n4 << 2) + idx; e < E; e += nthr) {
        int t = tgt[e];
        if (t >= lo && t < hi) {
            int pos = atomicAdd(&cursors[t], 1);
            unsigned q = (unsigned)(fdo[e] * 32767.0f + 0.5f);
            epack[pos] = (unsigned)src[e] | (q << 17);
        }
    }
}

// ---- K5: per-target aggregation, wave per node, 4 edges per iteration.
// Lane = (e2 = lane>>4: edge sub-index, g = batch, p = 16B chunk of the row).
// Phase 1: lane e decodes edge e, ONE float4 nodeinfo gather, writes both
// batches' coefs {src<<7, cc, cd} to wave-private LDS (zero-pad to 4).
// Phase 2: per iter each lane does broadcast b128 coef read + one dwordx4
// x gather (8 channels) + 16 FMA. Final shfl_xor(16/32) merges e2 partials.
__global__ __launch_bounds__(256) void aggregate_kernel(
    const float4* __restrict__ nodeinfo, const unsigned* __restrict__ epackFine,
    const unsigned* __restrict__ xb2, unsigned* __restrict__ up,
    unsigned* __restrict__ vp, int N) {
    const int lane = threadIdx.x & 63;
    const int wslot = threadIdx.x >> 6;
    const int node = blockIdx.x * 4 + wslot;
    __shared__ float4 s_e[4][2][64];
    if (node >= N) return;
    const int e2 = lane >> 4;       // 0..3
    const int q16 = lane & 15;
    const int g = q16 >> 3;         // batch
    const int p = q16 & 7;          // words 4p..4p+3 = channels 8p..8p+7
    float4 ni = nodeinfo[node];
    const unsigned wbits = (unsigned)__float_as_int(ni.w);
    const int start = (int)(wbits & 0x1FFFFFu);
    const int end = start + (int)(wbits >> 21);
    const float dt = ni.x, f0t = ni.y, f1t = ni.z;
    const char* xbg = (const char*)xb2 + (size_t)g * N * 128 + p * 16;
    float au[8] = {0, 0, 0, 0, 0, 0, 0, 0};
    float av[8] = {0, 0, 0, 0, 0, 0, 0, 0};
    for (int base = start; base < end; base += 64) {
        int cnt = min(64, end - base);
        int cntp = (cnt + 3) & ~3;
        if (lane < cnt) {
            unsigned pe = epackFine[base + lane];
            int s = (int)(pe & 0x1FFFFu);
            float fd = (float)(pe >> 17) * (1.0f / 32767.0f);
            float4 nis = nodeinfo[s];
            float nrm = nis.x * dt;
            float p0 = nis.y * f0t;
            float p1 = nis.z * f1t;
            float k0 = 1.0f / (1.0f + __expf(-2.0f * p0));  // (1+tanh)/2
            float k1 = 1.0f / (1.0f + __expf(-2.0f * p1));
            float w = 2.0f * fd - 1.0f;
            float f0 = fmaf(k0, w, 1.0f - fd);
            float f1 = fmaf(k1, w, 1.0f - fd);
            float soff = __int_as_float(s << 7);
            s_e[wslot][0][lane] = make_float4(soff, nrm * (1.0f - f0), nrm * f0, 0.f);
            s_e[wslot][1][lane] = make_float4(soff, nrm * (1.0f - f1), nrm * f1, 0.f);
        } else if (lane < cntp) {
            float4 z = make_float4(0.f, 0.f, 0.f, 0.f);
            s_e[wslot][0][lane] = z;
            s_e[wslot][1][lane] = z;
        }
        // wave-private LDS: in-wave write->read ordering via lgkmcnt only
        float4 r0 = s_e[wslot][g][e2];
        uint4 xwN = *(const uint4*)(xbg + __float_as_int(r0.x));
        float ccN = r0.y, cdN = r0.z;
        for (int j = 4; j < cntp; j += 4) {
            uint4 xw = xwN;
            float cc = ccN, cd = cdN;
            float4 r2 = s_e[wslot][g][j + e2];
            xwN = *(const uint4*)(xbg + __float_as_int(r2.x));  // prefetch
            ccN = r2.y; cdN = r2.z;
#pragma unroll
            for (int w = 0; w < 4; ++w) {
                unsigned xp = (&xw.x)[w];
                float lo = bflo(xp), hi = bfhi(xp);
                au[2 * w] = fmaf(cc, lo, au[2 * w]);
                au[2 * w + 1] = fmaf(cc, hi, au[2 * w + 1]);
                av[2 * w] = fmaf(cd, lo, av[2 * w]);
                av[2 * w + 1] = fmaf(cd, hi, av[2 * w + 1]);
            }
        }
#pragma unroll
        for (int w = 0; w < 4; ++w) {
            unsigned xp = (&xwN.x)[w];
            float lo = bflo(xp), hi = bfhi(xp);
            au[2 * w] = fmaf(ccN, lo, au[2 * w]);
            au[2 * w + 1] = fmaf(ccN, hi, au[2 * w + 1]);
            av[2 * w] = fmaf(cdN, lo, av[2 * w]);
            av[2 * w + 1] = fmaf(cdN, hi, av[2 * w + 1]);
        }
    }
    // merge the 4 edge-subset partials (lanes differing in bits 4,5)
#pragma unroll
    for (int k = 0; k < 8; ++k) {
        au[k] += __shfl_xor(au[k], 16, 64);
        au[k] += __shfl_xor(au[k], 32, 64);
        av[k] += __shfl_xor(av[k], 16, 64);
        av[k] += __shfl_xor(av[k], 32, 64);
    }
    if (e2 == 0) {
        uint4 xs = *(const uint4*)(xbg + ((size_t)node << 7));  // self-loop
        float d2 = dt * dt;
#pragma unroll
        for (int w = 0; w < 4; ++w) {
            unsigned xp = (&xs.x)[w];
            au[2 * w] = fmaf(d2, bflo(xp), au[2 * w]);
            au[2 * w + 1] = fmaf(d2, bfhi(xp), au[2 * w + 1]);
        }
        uint4 uo, vo;
        uo.x = pack_bf16x2(au[0], au[1]);
        uo.y = pack_bf16x2(au[2], au[3]);
        uo.z = pack_bf16x2(au[4], au[5]);
        uo.w = pack_bf16x2(au[6], au[7]);
        vo.x = pack_bf16x2(av[0], av[1]);
        vo.y = pack_bf16x2(av[2], av[3]);
        vo.z = pack_bf16x2(av[4], av[5]);
        vo.w = pack_bf16x2(av[6], av[7]);
        size_t wo = ((size_t)(g * N + node)) * 32 + 4 * p;
        *(uint4*)(up + wo) = uo;
        *(uint4*)(vp + wo) = vo;
    }
}

// ---- K6: MFMA GEMM. out = [u v] @ [Wc;Wd]^T + bias.
__device__ __forceinline__ short8 make_bfrag(const float* __restrict__ row, int off) {
    const float4* p = (const float4*)(row + off);
    float4 lo = p[0], hi = p[1];
    uint4 w;
    w.x = pack_bf16x2(lo.x, lo.y);
    w.y = pack_bf16x2(lo.z, lo.w);
    w.z = pack_bf16x2(hi.x, hi.y);
    w.w = pack_bf16x2(hi.z, hi.w);
    return __builtin_bit_cast(short8, w);
}

__global__ __launch_bounds__(256) void gemm_mfma_kernel(
    const unsigned* __restrict__ up, const unsigned* __restrict__ vp,
    const float* __restrict__ Wc, const float* __restrict__ Wd,
    const float* __restrict__ bias, float* __restrict__ out, int ntiles) {
    const int lane = threadIdx.x & 63;
    const int nl = lane & 15;
    const int quad = lane >> 4;
    const int wave = blockIdx.x * 4 + (threadIdx.x >> 6);
    const int nwaves = gridDim.x * 4;

    short8 bf[4][4];
    float bt[4];
#pragma unroll
    for (int t = 0; t < 4; ++t) {
        int n = 16 * t + nl;
        const float* wcr = Wc + n * 64;
        const float* wdr = Wd + n * 64;
        bf[0][t] = make_bfrag(wcr, quad * 8);
        bf[1][t] = make_bfrag(wcr, 32 + quad * 8);
        bf[2][t] = make_bfrag(wdr, quad * 8);
        bf[3][t] = make_bfrag(wdr, 32 + quad * 8);
        bt[t] = bias[n];
    }

    for (int tile = wave; tile < ntiles; tile += nwaves) {
        int row = tile * 16 + nl;
        const uint4* ur = (const uint4*)(up + (size_t)row * 32);
        const uint4* vr = (const uint4*)(vp + (size_t)row * 32);
        short8 a0 = __builtin_bit_cast(short8, ur[quad]);
        short8 a1 = __builtin_bit_cast(short8, ur[4 + quad]);
        short8 a2 = __builtin_bit_cast(short8, vr[quad]);
        short8 a3 = __builtin_bit_cast(short8, vr[4 + quad]);
        f32x4 acc[4];
#pragma unroll
        for (int t = 0; t < 4; ++t) {
            f32x4 z = {0.f, 0.f, 0.f, 0.f};
            acc[t] = __builtin_amdgcn_mfma_f32_16x16x32_bf16(a0, bf[0][t], z, 0, 0, 0);
            acc[t] = __builtin_amdgcn_mfma_f32_16x16x32_bf16(a1, bf[1][t], acc[t], 0, 0, 0);
            acc[t] = __builtin_amdgcn_mfma_f32_16x16x32_bf16(a2, bf[2][t], acc[t], 0, 0, 0);
            acc[t] = __builtin_amdgcn_mfma_f32_16x16x32_bf16(a3, bf[3][t], acc[t], 0, 0, 0);
        }
        float* ob = out + ((size_t)(tile * 16 + quad * 4) << 6);
#pragma unroll
        for (int t = 0; t < 4; ++t) {
            int col = 16 * t + nl;
#pragma unroll
            for (int r = 0; r < 4; ++r)
                ob[(r << 6) + col] = acc[t][r] + bt[t];
        }
    }
}

extern "C" void kernel_launch(void* const* d_in, const int* in_sizes, int n_in,
                              void* d_out, int out_size, void* d_ws, size_t ws_size,
                              hipStream_t stream) {
    const float* x = (const float*)d_in[0];
    const int* ei = (const int*)d_in[1];
    const float* fdo = (const float*)d_in[2];
    const float* flux = (const float*)d_in[3];
    const float* Wc = (const float*)d_in[4];
    const float* Wd = (const float*)d_in[5];
    const float* bias = (const float*)d_in[6];
    float* out = (float*)d_out;

    const int E = in_sizes[2];
    const int BN = in_sizes[3];
    const int N = BN / 2;
    const int W = (N + 7) / 8;  // target-range width per XCD partition

    auto align = [](size_t o) { return (o + 255) & ~(size_t)255; };
    char* ws = (char*)d_ws;
    size_t o = 0;
    int* degc = (int*)(ws + o);                    o = align(o + (size_t)(N + 1) * 4);
    float4* nodeinfo = (float4*)(ws + o);          o = align(o + (size_t)N * 16);
    unsigned* epack = (unsigned*)(ws + o);         o = align(o + (size_t)E * 4);
    unsigned* xb2 = (unsigned*)(ws + o);           o = align(o + (size_t)BN * 32 * 4);
    unsigned* up = (unsigned*)(ws + o);            o = align(o + (size_t)BN * 32 * 4);
    unsigned* vp = (unsigned*)(ws + o);            o += (size_t)BN * 32 * 4;
    // total ~46 MB

    const int* srcp = ei;
    const int* tgtp = ei + E;

    convert_kernel<<<2048, 256, 0, stream>>>(x, xb2, BN * 32, degc, N);
    degcount_kernel<<<2048, 256, 0, stream>>>(tgtp, degc, E, N, W);
    scan_kernel<<<(N + 255) / 256, 256, 0, stream>>>(degc, flux, nodeinfo, N);
    scatter_kernel<<<2048, 256, 0, stream>>>(srcp, tgtp, fdo, degc, epack, E, N, W);
    aggregate_kernel<<<(N + 3) / 4, 256, 0, stream>>>(nodeinfo, epack, xb2,
                                                      up, vp, N);
    gemm_mfma_kernel<<<512, 256, 0, stream>>>(up, vp, Wc, Wd, bias, out, BN / 16);
}

// Round 4
// 215.613 us; speedup vs baseline: 1.6759x; 1.4941x over previous
//
#include <hip/hip_runtime.h>
#include <math.h>

// ReaReaConv via linearity factorization + two-level owner-scatter binning:
//   u[b,t,:] = dis_t^2 * x[b,t,:] + sum_e norm_e*(1-f_be)*x[b,src_e,:]
//   v[b,t,:] =                      sum_e norm_e*   f_be *x[b,src_e,:]
//   out      = bias + u @ Wc^T + v @ Wd^T   (MFMA bf16, M=BN,K=128,N=64)
// Binning: binA1 buckets edges into 391x128-node slabs with block-local
// contiguous runs (no write amplification -- direct random-order CSR scatter
// measured 13x WRITE amplification from temporal spread of 4B stores).
// binA2 (NEW vs 225us baseline): 256-thread LDS-RESIDENT counting sort per
// bucket -- one slab read into LDS, LDS histogram + scan + in-LDS scatter,
// one coalesced streaming writeout. Replaces the old 1024-thread 3-global-pass
// sorter (16-wave barriers, 2x slab re-read, scattered 4B global writes).
// nodeinfo: {rsqrt(deg+1), flux0, flux1, deg<<21|rowstart}, rowstart<2^21.

constexpr int C = 64;
constexpr int CNB = 128;    // nodes per coarse bucket
constexpr int CCAP = 5120;  // entries per bucket (Poisson mean 4096, +16 sigma)

typedef short short8 __attribute__((ext_vector_type(8)));
typedef float f32x4 __attribute__((ext_vector_type(4)));

__device__ __forceinline__ unsigned pack_bf16x2(float a, float b) {
    unsigned ua = __float_as_uint(a);
    ua = (ua + 0x7fffu + ((ua >> 16) & 1u)) >> 16;  // RNE
    unsigned ub = __float_as_uint(b);
    ub = (ub + 0x7fffu + ((ub >> 16) & 1u)) >> 16;
    return ua | (ub << 16);
}
__device__ __forceinline__ float bflo(unsigned p) { return __uint_as_float(p << 16); }
__device__ __forceinline__ float bfhi(unsigned p) { return __uint_as_float(p & 0xffff0000u); }

// ---- K1: x -> packed bf16x2 (natural pairs) + zero the coarse cursors
__global__ __launch_bounds__(256) void convert_kernel(
    const float* __restrict__ x, unsigned* __restrict__ xb2, int nwords,
    int* __restrict__ coarseCursor, int ncoarse) {
    int i = blockIdx.x * blockDim.x + threadIdx.x;
    if (i < ncoarse) coarseCursor[i] = 0;
    int stride = gridDim.x * blockDim.x;
    const float2* x2 = (const float2*)x;
    for (int w = i; w < nwords; w += stride) {
        float2 xv = x2[w];
        xb2[w] = pack_bf16x2(xv.x, xv.y);
    }
}

// ---- K2 (A1): coarse binning into 391 buckets of 128 nodes. Per-block LDS
// histogram -> one global cursor atomic per (block,bucket) -> 8B entries in
// ~21-entry runs (contiguous per block => ~1 writer per 64B line).
__global__ __launch_bounds__(256) void binA1_kernel(
    const int* __restrict__ src, const int* __restrict__ tgt,
    const float* __restrict__ fdo, int* __restrict__ coarseCursor,
    unsigned long long* __restrict__ slab, int E, int ncoarse) {
    __shared__ int hcnt[512];
    __shared__ int hbase[512];
    const int tid = threadIdx.x;
    const int chunk0 = blockIdx.x * 8192;
    for (int c = tid; c < 512; c += 256) hcnt[c] = 0;
    __syncthreads();
#pragma unroll 4
    for (int k = 0; k < 32; ++k) {
        int e = chunk0 + tid + k * 256;
        if (e < E) atomicAdd(&hcnt[tgt[e] >> 7], 1);
    }
    __syncthreads();
    for (int c = tid; c < ncoarse; c += 256) {
        int cc = hcnt[c];
        hbase[c] = cc ? atomicAdd(&coarseCursor[c], cc) : 0;
        hcnt[c] = 0;  // reuse as rank cursor
    }
    __syncthreads();
#pragma unroll 4
    for (int k = 0; k < 32; ++k) {
        int e = chunk0 + tid + k * 256;
        if (e < E) {
            int t = tgt[e];
            int b = t >> 7;
            int pos = hbase[b] + atomicAdd(&hcnt[b], 1);
            if (pos < CCAP) {
                unsigned q = (unsigned)(fdo[e] * 32767.0f + 0.5f);  // 15-bit
                unsigned long long en = (unsigned long long)(unsigned)src[e]
                                      | ((unsigned long long)(unsigned)(t & 127) << 17)
                                      | ((unsigned long long)q << 24);
                slab[(size_t)b * CCAP + pos] = en;
            }
        }
    }
}

// ---- K3 (A2): one 256-thread block per coarse bucket. LDS-resident counting
// sort: load slab entries once -> LDS histogram -> 128-wide scan -> in-LDS
// scatter -> coalesced writeout of sorted 4B entries; emit nodeinfo.
__global__ __launch_bounds__(256) void binA2_kernel(
    const unsigned long long* __restrict__ slab,
    const int* __restrict__ coarseCursor, const float* __restrict__ flux,
    unsigned* __restrict__ epackFine, float4* __restrict__ nodeinfo, int N) {
    const int b = blockIdx.x;
    const int tid = threadIdx.x;
    __shared__ unsigned long long e8[CCAP];  // 40 KB
    __shared__ unsigned eout[CCAP];          // 20 KB
    __shared__ int ncnt[CNB];
    __shared__ int nsc[CNB];
    __shared__ int ncur[CNB];
    int cnt = min(coarseCursor[b], CCAP);
    if (tid < CNB) { ncnt[tid] = 0; ncur[tid] = 0; }
    __syncthreads();
    const unsigned long long* sl = slab + (size_t)b * CCAP;
    for (int i = tid; i < cnt; i += 256) {
        unsigned long long e = sl[i];
        e8[i] = e;
        atomicAdd(&ncnt[(int)((e >> 17) & 127)], 1);
    }
    __syncthreads();
    if (tid < CNB) nsc[tid] = ncnt[tid];
    __syncthreads();
    for (int off = 1; off < CNB; off <<= 1) {  // Hillis-Steele inclusive
        int v = (tid < CNB && tid >= off) ? nsc[tid - off] : 0;
        __syncthreads();
        if (tid < CNB) nsc[tid] += v;
        __syncthreads();
    }
    for (int i = tid; i < cnt; i += 256) {
        unsigned long long e = e8[i];
        int tl = (int)((e >> 17) & 127);
        int pos = (nsc[tl] - ncnt[tl]) + atomicAdd(&ncur[tl], 1);
        eout[pos] = (unsigned)(e & 0x1FFFFull)
                  | ((unsigned)((e >> 24) & 0x7FFF) << 17);
    }
    if (tid < CNB) {
        int n = b * CNB + tid;
        if (n < N) {
            int dg = ncnt[tid];
            int rs = b * CCAP + (nsc[tid] - dg);  // 391*5120 < 2^21
            float4 ni;
            ni.x = rsqrtf((float)(dg + 1));
            ni.y = flux[n];
            ni.z = flux[N + n];
            ni.w = __int_as_float((dg << 21) | rs);
            nodeinfo[n] = ni;
        }
    }
    __syncthreads();
    unsigned* out = epackFine + (size_t)b * CCAP;
    for (int i = tid; i < cnt; i += 256) out[i] = eout[i];
}

// ---- K4: per-target aggregation, wave per node, 4 edges per iteration.
// Lane = (e2 = lane>>4: edge sub-index, g = batch, p = 16B chunk of the row).
// Phase 1: lane e decodes edge e, ONE float4 nodeinfo gather, writes both
// batches' coefs {src<<7, cc, cd} to wave-private LDS (zero-pad to 4).
// Phase 2: per iter each lane does broadcast b128 coef read + one dwordx4
// x gather (8 channels) + 16 FMA. Final shfl_xor(16/32) merges e2 partials.
__global__ __launch_bounds__(256) void aggregate_kernel(
    const float4* __restrict__ nodeinfo, const unsigned* __restrict__ epackFine,
    const unsigned* __restrict__ xb2, unsigned* __restrict__ up,
    unsigned* __restrict__ vp, int N) {
    const int lane = threadIdx.x & 63;
    const int wslot = threadIdx.x >> 6;
    const int node = blockIdx.x * 4 + wslot;
    __shared__ float4 s_e[4][2][64];
    if (node >= N) return;
    const int e2 = lane >> 4;       // 0..3
    const int q16 = lane & 15;
    const int g = q16 >> 3;         // batch
    const int p = q16 & 7;          // words 4p..4p+3 = channels 8p..8p+7
    float4 ni = nodeinfo[node];
    const unsigned wbits = (unsigned)__float_as_int(ni.w);
    const int start = (int)(wbits & 0x1FFFFFu);
    const int end = start + (int)(wbits >> 21);
    const float dt = ni.x, f0t = ni.y, f1t = ni.z;
    const char* xbg = (const char*)xb2 + (size_t)g * N * 128 + p * 16;
    float au[8] = {0, 0, 0, 0, 0, 0, 0, 0};
    float av[8] = {0, 0, 0, 0, 0, 0, 0, 0};
    for (int base = start; base < end; base += 64) {
        int cnt = min(64, end - base);
        int cntp = (cnt + 3) & ~3;
        if (lane < cnt) {
            unsigned pe = epackFine[base + lane];
            int s = (int)(pe & 0x1FFFFu);
            float fd = (float)(pe >> 17) * (1.0f / 32767.0f);
            float4 nis = nodeinfo[s];
            float nrm = nis.x * dt;
            float p0 = nis.y * f0t;
            float p1 = nis.z * f1t;
            float k0 = 1.0f / (1.0f + __expf(-2.0f * p0));  // (1+tanh)/2
            float k1 = 1.0f / (1.0f + __expf(-2.0f * p1));
            float w = 2.0f * fd - 1.0f;
            float f0 = fmaf(k0, w, 1.0f - fd);
            float f1 = fmaf(k1, w, 1.0f - fd);
            float soff = __int_as_float(s << 7);
            s_e[wslot][0][lane] = make_float4(soff, nrm * (1.0f - f0), nrm * f0, 0.f);
            s_e[wslot][1][lane] = make_float4(soff, nrm * (1.0f - f1), nrm * f1, 0.f);
        } else if (lane < cntp) {
            float4 z = make_float4(0.f, 0.f, 0.f, 0.f);
            s_e[wslot][0][lane] = z;
            s_e[wslot][1][lane] = z;
        }
        // wave-private LDS: in-wave write->read ordering via lgkmcnt only
        float4 r0 = s_e[wslot][g][e2];
        uint4 xwN = *(const uint4*)(xbg + __float_as_int(r0.x));
        float ccN = r0.y, cdN = r0.z;
        for (int j = 4; j < cntp; j += 4) {
            uint4 xw = xwN;
            float cc = ccN, cd = cdN;
            float4 r2 = s_e[wslot][g][j + e2];
            xwN = *(const uint4*)(xbg + __float_as_int(r2.x));  // prefetch
            ccN = r2.y; cdN = r2.z;
#pragma unroll
            for (int w = 0; w < 4; ++w) {
                unsigned xp = (&xw.x)[w];
                float lo = bflo(xp), hi = bfhi(xp);
                au[2 * w] = fmaf(cc, lo, au[2 * w]);
                au[2 * w + 1] = fmaf(cc, hi, au[2 * w + 1]);
                av[2 * w] = fmaf(cd, lo, av[2 * w]);
                av[2 * w + 1] = fmaf(cd, hi, av[2 * w + 1]);
            }
        }
#pragma unroll
        for (int w = 0; w < 4; ++w) {
            unsigned xp = (&xwN.x)[w];
            float lo = bflo(xp), hi = bfhi(xp);
            au[2 * w] = fmaf(ccN, lo, au[2 * w]);
            au[2 * w + 1] = fmaf(ccN, hi, au[2 * w + 1]);
            av[2 * w] = fmaf(cdN, lo, av[2 * w]);
            av[2 * w + 1] = fmaf(cdN, hi, av[2 * w + 1]);
        }
    }
    // merge the 4 edge-subset partials (lanes differing in bits 4,5)
#pragma unroll
    for (int k = 0; k < 8; ++k) {
        au[k] += __shfl_xor(au[k], 16, 64);
        au[k] += __shfl_xor(au[k], 32, 64);
        av[k] += __shfl_xor(av[k], 16, 64);
        av[k] += __shfl_xor(av[k], 32, 64);
    }
    if (e2 == 0) {
        uint4 xs = *(const uint4*)(xbg + ((size_t)node << 7));  // self-loop
        float d2 = dt * dt;
#pragma unroll
        for (int w = 0; w < 4; ++w) {
            unsigned xp = (&xs.x)[w];
            au[2 * w] = fmaf(d2, bflo(xp), au[2 * w]);
            au[2 * w + 1] = fmaf(d2, bfhi(xp), au[2 * w + 1]);
        }
        uint4 uo, vo;
        uo.x = pack_bf16x2(au[0], au[1]);
        uo.y = pack_bf16x2(au[2], au[3]);
        uo.z = pack_bf16x2(au[4], au[5]);
        uo.w = pack_bf16x2(au[6], au[7]);
        vo.x = pack_bf16x2(av[0], av[1]);
        vo.y = pack_bf16x2(av[2], av[3]);
        vo.z = pack_bf16x2(av[4], av[5]);
        vo.w = pack_bf16x2(av[6], av[7]);
        size_t wo = ((size_t)(g * N + node)) * 32 + 4 * p;
        *(uint4*)(up + wo) = uo;
        *(uint4*)(vp + wo) = vo;
    }
}

// ---- K5: MFMA GEMM. out = [u v] @ [Wc;Wd]^T + bias.
__device__ __forceinline__ short8 make_bfrag(const float* __restrict__ row, int off) {
    const float4* p = (const float4*)(row + off);
    float4 lo = p[0], hi = p[1];
    uint4 w;
    w.x = pack_bf16x2(lo.x, lo.y);
    w.y = pack_bf16x2(lo.z, lo.w);
    w.z = pack_bf16x2(hi.x, hi.y);
    w.w = pack_bf16x2(hi.z, hi.w);
    return __builtin_bit_cast(short8, w);
}

__global__ __launch_bounds__(256) void gemm_mfma_kernel(
    const unsigned* __restrict__ up, const unsigned* __restrict__ vp,
    const float* __restrict__ Wc, const float* __restrict__ Wd,
    const float* __restrict__ bias, float* __restrict__ out, int ntiles) {
    const int lane = threadIdx.x & 63;
    const int nl = lane & 15;
    const int quad = lane >> 4;
    const int wave = blockIdx.x * 4 + (threadIdx.x >> 6);
    const int nwaves = gridDim.x * 4;

    short8 bf[4][4];
    float bt[4];
#pragma unroll
    for (int t = 0; t < 4; ++t) {
        int n = 16 * t + nl;
        const float* wcr = Wc + n * 64;
        const float* wdr = Wd + n * 64;
        bf[0][t] = make_bfrag(wcr, quad * 8);
        bf[1][t] = make_bfrag(wcr, 32 + quad * 8);
        bf[2][t] = make_bfrag(wdr, quad * 8);
        bf[3][t] = make_bfrag(wdr, 32 + quad * 8);
        bt[t] = bias[n];
    }

    for (int tile = wave; tile < ntiles; tile += nwaves) {
        int row = tile * 16 + nl;
        const uint4* ur = (const uint4*)(up + (size_t)row * 32);
        const uint4* vr = (const uint4*)(vp + (size_t)row * 32);
        short8 a0 = __builtin_bit_cast(short8, ur[quad]);
        short8 a1 = __builtin_bit_cast(short8, ur[4 + quad]);
        short8 a2 = __builtin_bit_cast(short8, vr[quad]);
        short8 a3 = __builtin_bit_cast(short8, vr[4 + quad]);
        f32x4 acc[4];
#pragma unroll
        for (int t = 0; t < 4; ++t) {
            f32x4 z = {0.f, 0.f, 0.f, 0.f};
            acc[t] = __builtin_amdgcn_mfma_f32_16x16x32_bf16(a0, bf[0][t], z, 0, 0, 0);
            acc[t] = __builtin_amdgcn_mfma_f32_16x16x32_bf16(a1, bf[1][t], acc[t], 0, 0, 0);
            acc[t] = __builtin_amdgcn_mfma_f32_16x16x32_bf16(a2, bf[2][t], acc[t], 0, 0, 0);
            acc[t] = __builtin_amdgcn_mfma_f32_16x16x32_bf16(a3, bf[3][t], acc[t], 0, 0, 0);
        }
        float* ob = out + ((size_t)(tile * 16 + quad * 4) << 6);
#pragma unroll
        for (int t = 0; t < 4; ++t) {
            int col = 16 * t + nl;
#pragma unroll
            for (int r = 0; r < 4; ++r)
                ob[(r << 6) + col] = acc[t][r] + bt[t];
        }
    }
}

extern "C" void kernel_launch(void* const* d_in, const int* in_sizes, int n_in,
                              void* d_out, int out_size, void* d_ws, size_t ws_size,
                              hipStream_t stream) {
    const float* x = (const float*)d_in[0];
    const int* ei = (const int*)d_in[1];
    const float* fdo = (const float*)d_in[2];
    const float* flux = (const float*)d_in[3];
    const float* Wc = (const float*)d_in[4];
    const float* Wd = (const float*)d_in[5];
    const float* bias = (const float*)d_in[6];
    float* out = (float*)d_out;

    const int E = in_sizes[2];
    const int BN = in_sizes[3];
    const int N = BN / 2;
    const int ncoarse = (N + CNB - 1) / CNB;  // 391

    auto align = [](size_t o) { return (o + 255) & ~(size_t)255; };
    char* ws = (char*)d_ws;
    size_t o = 0;
    int* coarseCursor = (int*)(ws + o);            o = align(o + (size_t)ncoarse * 4);
    float4* nodeinfo = (float4*)(ws + o);          o = align(o + (size_t)N * 16);
    unsigned long long* slab = (unsigned long long*)(ws + o);
    unsigned* up = (unsigned*)slab;                // overlay: slab dead after A2
    o = align(o + (size_t)ncoarse * CCAP * 8);     // 16.0 MB >= up 12.8 MB
    unsigned* epackFine = (unsigned*)(ws + o);     o = align(o + (size_t)ncoarse * CCAP * 4);
    unsigned* xb2 = (unsigned*)(ws + o);           o = align(o + (size_t)BN * 32 * 4);
    unsigned* vp = (unsigned*)(ws + o);            o += (size_t)BN * 32 * 4;
    // total ~50.4 MB

    const int* srcp = ei;
    const int* tgtp = ei + E;

    convert_kernel<<<2048, 256, 0, stream>>>(x, xb2, BN * 32, coarseCursor, ncoarse);
    binA1_kernel<<<(E + 8191) / 8192, 256, 0, stream>>>(srcp, tgtp, fdo,
                                                        coarseCursor, slab, E, ncoarse);
    binA2_kernel<<<ncoarse, 256, 0, stream>>>(slab, coarseCursor, flux,
                                              epackFine, nodeinfo, N);
    aggregate_kernel<<<(N + 3) / 4, 256, 0, stream>>>(nodeinfo, epackFine, xb2,
                                                      up, vp, N);
    gemm_mfma_kernel<<<512, 256, 0, stream>>>(up, vp, Wc, Wd, bias, out, BN / 16);
}